// Round 7
// baseline (315.737 us; speedup 1.0000x reference)
//
#include <hip/hip_runtime.h>
#include <stdint.h>

// Dyna_Dec: out[b,d,l] = sum_c x[b,c,l] * w[l,c,d] + bias[l,d]
// B=128, C=32, L=4096. fp32 in/out.
//
// R6 (88us): W lane-scattered -> L1 serialization.
// R7 (104us): LDS staging fixed scatter; spilled.
// R8 (115us): spill fixed; serial convoy, no overlap.
// R9 (71us): dbuf + global_load_lds(16) + pre-swizzled src.
// R10 (182us): counted vmcnt; sub-array refs -> scratch. Invalid.
// R11 (74.6us): counted vmcnt spill-free == R9 -> wait-type irrelevant.
// R12 (58us): kNB 8 (double tile). Amortization pays. BUT: issue/CU ~9us
//   vs 58us wall -> 85% exposed stall, unexplained by any data-side
//   resource (L2 stage ~8us, x-L1 ~7us, LDS conflicts ~2us, HBM ~17us).
//
// R13 theory: I$ streaming. Fully-unrolled body = 16 phases x ~330 inst
//   ~= 40 KB code vs 32 KB I$; every wave streams it once (zero reuse),
//   16 waves/CU at staggered offsets -> continuous I$ capacity misses,
//   ~200cy L2 code fetch every ~dozen instructions. Explains: R11 null
//   (same code size), R12 gain (more FMA per fetched byte), stall
//   immunity to data-side fixes.
//   Fix: re-roll phases 1..12 into a 6-iter loop (2 phases/body so
//   x0/x1 + ldsA/B stay statically named; cb scalar induction).
//   ~5 KB code -> I$-resident. Schedule/waits/swizzle IDENTICAL to R12.

namespace {

constexpr int kC  = 32;
constexpr int kL  = 4096;
constexpr int kNB = 8;   // batches per thread
constexpr int kND = 8;   // d-channels per thread
constexpr int kCC = 2;   // c's per staged chunk
constexpr int kLB = 64;  // l-positions per block
constexpr int kChunkFloats = kLB * kCC * kC;      // 4096 floats = 16 KB

__device__ __forceinline__ void async_ld16(const float* g, float* l) {
    __builtin_amdgcn_global_load_lds(
        (__attribute__((address_space(1))) const void*)g,
        (__attribute__((address_space(3))) void*)l, 16, 0, 0);
}

#define SCHEDFENCE() __builtin_amdgcn_sched_barrier(0)
#define WAITV(N) asm volatile("s_waitcnt vmcnt(" #N ")" ::: "memory")
#define BAR() do { __builtin_amdgcn_s_barrier(); SCHEDFENCE(); } while (0)

__global__ __launch_bounds__(256, 4)
void dyna_dec(const float* __restrict__ x,
              const float* __restrict__ w,
              const float* __restrict__ bias,
              float* __restrict__ out) {
    __shared__ __align__(16) float ldsA[kChunkFloats];
    __shared__ __align__(16) float ldsB[kChunkFloats];

    const int tid = threadIdx.x;
    const int lt  = tid & 63;          // lane = l within chunk (coalescing dim)
    const int dg  = tid >> 6;          // wave = d-group 0..3
    const int l   = blockIdx.x * kLB + lt;      // gridDim.x = 64
    const int b0  = blockIdx.y * kNB;           // gridDim.y = 16
    const int d0  = dg * kND;

    const float* xp = x + (size_t)b0 * (kC * kL) + l;
    const float* wb = w + (size_t)blockIdx.x * kLB * (kC * kC);

    // Staging geometry (verified R9/R11/R12, absmax 0): 1024 16B-slots per
    // chunk. Wave dg, call k, lane lt fills slot s = dg*256 + k*64 + lt
    // (DMA: uniform base + lane*16). Slot s holds W[ls, cb*kCC+cs,
    // 4*(dsl^(ls&7))..+4) with ls=s>>4, cs=(s>>3)&1, dsl=s&7.
    int goff[4];
    const int ldsbase = dg * 1024;
#pragma unroll
    for (int k = 0; k < 4; ++k) {
        const int s   = dg * 256 + k * 64 + lt;
        const int ls  = s >> 4;
        const int cs  = (s >> 3) & 1;
        const int dsl = s & 7;
        goff[k] = ls * (kC * kC) + cs * kC + ((dsl ^ (ls & 7)) << 2);
    }

#define STAGE(BUF, CB) do {                                                  \
    _Pragma("unroll")                                                        \
    for (int k_ = 0; k_ < 4; ++k_)                                           \
        async_ld16(wb + (CB) * (kCC * kC) + goff[k_],                        \
                   (BUF) + ldsbase + k_ * 256);                              \
} while (0)

    float x0[kCC][kNB], x1[kCC][kNB];

#define XLOAD(XR, CB) do {                                                   \
    _Pragma("unroll")                                                        \
    for (int c_ = 0; c_ < kCC; ++c_)                                         \
        _Pragma("unroll")                                                    \
        for (int i_ = 0; i_ < kNB; ++i_)                                     \
            XR[c_][i_] = xp[(size_t)i_ * (kC * kL) +                         \
                            (size_t)((CB) * kCC + c_) * kL];                 \
} while (0)

    float acc[kNB][kND];
#pragma unroll
    for (int i = 0; i < kNB; ++i)
#pragma unroll
        for (int j = 0; j < kND; ++j) acc[i][j] = 0.0f;

#define COMPUTE(BUF, XR) do {                                                \
    _Pragma("unroll")                                                        \
    for (int c_ = 0; c_ < kCC; ++c_) {                                       \
        const int sl0_ = lt * 16 + c_ * 8 + ((2 * dg) ^ (lt & 7));           \
        const int sl1_ = lt * 16 + c_ * 8 + ((2 * dg + 1) ^ (lt & 7));       \
        const float4 w0_ =                                                   \
            *reinterpret_cast<const float4*>((BUF) + sl0_ * 4);              \
        const float4 w1_ =                                                   \
            *reinterpret_cast<const float4*>((BUF) + sl1_ * 4);              \
        _Pragma("unroll")                                                    \
        for (int i_ = 0; i_ < kNB; ++i_) {                                   \
            const float xv_ = XR[c_][i_];                                    \
            acc[i_][0] += xv_ * w0_.x;  acc[i_][1] += xv_ * w0_.y;           \
            acc[i_][2] += xv_ * w0_.z;  acc[i_][3] += xv_ * w0_.w;           \
            acc[i_][4] += xv_ * w1_.x;  acc[i_][5] += xv_ * w1_.y;           \
            acc[i_][6] += xv_ * w1_.z;  acc[i_][7] += xv_ * w1_.w;           \
        }                                                                    \
    }                                                                        \
} while (0)

    // Prologue: stage chunk 0, x chunks 0 and 1 in flight (36 VMEM).
    STAGE(ldsA, 0); SCHEDFENCE();
    XLOAD(x0, 0);
    XLOAD(x1, 1); SCHEDFENCE();

    // Phase 0: outstanding [stage0 x4, x0 x16, x1 x16] -> vmcnt(32)
    // completes stage0 (x RAW handled by compiler-inserted waits).
    WAITV(32); BAR();
    STAGE(ldsB, 1); SCHEDFENCE();
    COMPUTE(ldsA, x0); XLOAD(x0, 2); SCHEDFENCE();

    // Phases 1..12 as a ROLLED loop (6 iters x 2 phases). Odd phase t:
    // compute B(chunk t) w/ x1, stage A<-t+1, xload x1<-t+2. Even phase
    // t+1: compute A(chunk t+1) w/ x0, stage B<-t+2, xload x0<-t+3.
#pragma unroll 1
    for (int t = 1; t <= 11; t += 2) {
        WAITV(16); BAR();
        STAGE(ldsA, t + 1); SCHEDFENCE();
        COMPUTE(ldsB, x1); XLOAD(x1, t + 2); SCHEDFENCE();

        WAITV(16); BAR();
        STAGE(ldsB, t + 2); SCHEDFENCE();
        COMPUTE(ldsA, x0); XLOAD(x0, t + 3); SCHEDFENCE();
    }

    // Phase 13: compute chunk 13, stage 14, xload x1<-15.
    WAITV(16); BAR();
    STAGE(ldsA, 14); SCHEDFENCE();
    COMPUTE(ldsB, x1); XLOAD(x1, 15); SCHEDFENCE();

    // Phase 14: stage chunk 15, compute chunk 14.
    WAITV(16); BAR();
    STAGE(ldsB, 15); SCHEDFENCE();
    COMPUTE(ldsA, x0); SCHEDFENCE();

    // Phase 15: drain, compute last chunk.
    WAITV(0); BAR();
    COMPUTE(ldsB, x1);

    // Epilogue: bias + coalesced store.
    const float4 b0v = *reinterpret_cast<const float4*>(bias + (size_t)l * kC + d0);
    const float4 b1v = *reinterpret_cast<const float4*>(bias + (size_t)l * kC + d0 + 4);
    const float bv[kND] = {b0v.x, b0v.y, b0v.z, b0v.w, b1v.x, b1v.y, b1v.z, b1v.w};

#pragma unroll
    for (int i = 0; i < kNB; ++i) {
        float* op = out + (size_t)(b0 + i) * (kC * kL) + l;
#pragma unroll
        for (int j = 0; j < kND; ++j)
            op[(size_t)(d0 + j) * kL] = acc[i][j] + bv[j];  // coalesced over l
    }

#undef STAGE
#undef XLOAD
#undef COMPUTE
}

}  // namespace

extern "C" void kernel_launch(void* const* d_in, const int* in_sizes, int n_in,
                              void* d_out, int out_size, void* d_ws, size_t ws_size,
                              hipStream_t stream) {
    // inputs: 0=x (B,C,H,W) fp32, 1=px (unused), 2=weight (L*C, C) fp32,
    //         3=bias (L*C) fp32
    const float* x    = (const float*)d_in[0];
    const float* wgt  = (const float*)d_in[2];
    const float* bias = (const float*)d_in[3];
    float* out = (float*)d_out;

    dim3 grid(kL / 64, 128 / kNB);  // 64 x 16 = 1024 blocks = 4/CU
    dim3 block(256);
    hipLaunchKernelGGL(dyna_dec, grid, block, 0, stream, x, wgt, bias, out);
}

// Round 8
// 265.408 us; speedup vs baseline: 1.1896x; 1.1896x over previous
//
#include <hip/hip_runtime.h>
#include <stdint.h>

// Dyna_Dec: out[b,d,l] = sum_c x[b,c,l] * w[l,c,d] + bias[l,d]
// B=128, C=32, L=4096. fp32 in/out.
//
// R6 (88us): W lane-scattered -> L1 serialization.
// R9 (71us): dbuf + global_load_lds(16) + pre-swizzled src.
// R11 (74.6us): counted vmcnt spill-free == R9 -> wait-type irrelevant.
// R12 (58us): kNB 8. Best valid. 85% exposed stall, no data-side resource
//   explains it. Theory: I$ streaming (~30-40KB unrolled body vs 32KB I$,
//   zero temporal reuse, 16 staggered waves -> continuous code fetch).
// R13 (221us): I$ test INVALID: 2-phase body w/ two 2-ahead x-sets +
//   pinned sched -> liveness > 128 VGPR cap -> acc spilled (WRITE 382MB).
//
// R14: valid I$ test. R12's schedule, minimal loop-carried state:
//   - ONE x set xc[2][8], issued ~0.5 phase ahead (before the top-of-phase
//     wait): FIFO at wait = [stage(t) x4 older, x x16 younger] ->
//     vmcnt(16) completes stage(t), leaves x in flight (exact, constant).
//   - 2-phase rolled body (7 iters, phases 0..13; 14/15 peeled) so
//     ldsA/ldsB are statically named. No pointer swap, no sub-array refs,
//     constant indices only (rule #20).
//   - Live state ~95 VGPR < 128 cap. Code ~7KB -> I$-resident.
//   Gates: WRITE == 65536 KB exactly, VGPR <= 128, absmax 0.

namespace {

constexpr int kC  = 32;
constexpr int kL  = 4096;
constexpr int kNB = 8;   // batches per thread
constexpr int kND = 8;   // d-channels per thread
constexpr int kCC = 2;   // c's per staged chunk
constexpr int kLB = 64;  // l-positions per block
constexpr int kChunkFloats = kLB * kCC * kC;      // 4096 floats = 16 KB

__device__ __forceinline__ void async_ld16(const float* g, float* l) {
    __builtin_amdgcn_global_load_lds(
        (__attribute__((address_space(1))) const void*)g,
        (__attribute__((address_space(3))) void*)l, 16, 0, 0);
}

#define SCHEDFENCE() __builtin_amdgcn_sched_barrier(0)
#define WAITV(N) asm volatile("s_waitcnt vmcnt(" #N ")" ::: "memory")
#define BAR() do { __builtin_amdgcn_s_barrier(); SCHEDFENCE(); } while (0)

__global__ __launch_bounds__(256, 4)
void dyna_dec(const float* __restrict__ x,
              const float* __restrict__ w,
              const float* __restrict__ bias,
              float* __restrict__ out) {
    __shared__ __align__(16) float ldsA[kChunkFloats];
    __shared__ __align__(16) float ldsB[kChunkFloats];

    const int tid = threadIdx.x;
    const int lt  = tid & 63;          // lane = l within chunk (coalescing dim)
    const int dg  = tid >> 6;          // wave = d-group 0..3
    const int l   = blockIdx.x * kLB + lt;      // gridDim.x = 64
    const int b0  = blockIdx.y * kNB;           // gridDim.y = 16
    const int d0  = dg * kND;

    const float* xp = x + (size_t)b0 * (kC * kL) + l;
    const float* wb = w + (size_t)blockIdx.x * kLB * (kC * kC);

    // Staging geometry (verified R9/R11/R12, absmax 0): 1024 16B-slots per
    // chunk. Wave dg, call k, lane lt fills slot s = dg*256 + k*64 + lt
    // (DMA: uniform base + lane*16). Slot s holds W[ls, cb*kCC+cs,
    // 4*(dsl^(ls&7))..+4) with ls=s>>4, cs=(s>>3)&1, dsl=s&7.
    int goff[4];
    const int ldsbase = dg * 1024;
#pragma unroll
    for (int k = 0; k < 4; ++k) {
        const int s   = dg * 256 + k * 64 + lt;
        const int ls  = s >> 4;
        const int cs  = (s >> 3) & 1;
        const int dsl = s & 7;
        goff[k] = ls * (kC * kC) + cs * kC + ((dsl ^ (ls & 7)) << 2);
    }

#define STAGE(BUF, CB) do {                                                  \
    _Pragma("unroll")                                                        \
    for (int k_ = 0; k_ < 4; ++k_)                                           \
        async_ld16(wb + (CB) * (kCC * kC) + goff[k_],                        \
                   (BUF) + ldsbase + k_ * 256);                              \
} while (0)

    float xc[kCC][kNB];

#define XLOAD(CB) do {                                                       \
    _Pragma("unroll")                                                        \
    for (int c_ = 0; c_ < kCC; ++c_)                                         \
        _Pragma("unroll")                                                    \
        for (int i_ = 0; i_ < kNB; ++i_)                                     \
            xc[c_][i_] = xp[(size_t)i_ * (kC * kL) +                         \
                            (size_t)((CB) * kCC + c_) * kL];                 \
} while (0)

    float acc[kNB][kND];
#pragma unroll
    for (int i = 0; i < kNB; ++i)
#pragma unroll
        for (int j = 0; j < kND; ++j) acc[i][j] = 0.0f;

#define COMPUTE(BUF) do {                                                    \
    _Pragma("unroll")                                                        \
    for (int c_ = 0; c_ < kCC; ++c_) {                                       \
        const int sl0_ = lt * 16 + c_ * 8 + ((2 * dg) ^ (lt & 7));           \
        const int sl1_ = lt * 16 + c_ * 8 + ((2 * dg + 1) ^ (lt & 7));       \
        const float4 w0_ =                                                   \
            *reinterpret_cast<const float4*>((BUF) + sl0_ * 4);              \
        const float4 w1_ =                                                   \
            *reinterpret_cast<const float4*>((BUF) + sl1_ * 4);              \
        _Pragma("unroll")                                                    \
        for (int i_ = 0; i_ < kNB; ++i_) {                                   \
            const float xv_ = xc[c_][i_];                                    \
            acc[i_][0] += xv_ * w0_.x;  acc[i_][1] += xv_ * w0_.y;           \
            acc[i_][2] += xv_ * w0_.z;  acc[i_][3] += xv_ * w0_.w;           \
            acc[i_][4] += xv_ * w1_.x;  acc[i_][5] += xv_ * w1_.y;           \
            acc[i_][6] += xv_ * w1_.z;  acc[i_][7] += xv_ * w1_.w;           \
        }                                                                    \
    }                                                                        \
} while (0)

    // One phase: x(t) issued BEFORE the wait (gets wait+barrier+stage as
    // cover); vmcnt(16) completes stage(t) exactly (4 older stage ops,
    // 16 younger x ops); stage(t+1) after the barrier (WAR-safe: all
    // waves' phase-t-1 LDS reads were consumed pre-barrier).
#define PHASE_STG(CUR, NXT, T) do {                                          \
    XLOAD(T); SCHEDFENCE();                                                  \
    WAITV(16); BAR();                                                        \
    STAGE(NXT, (T) + 1); SCHEDFENCE();                                       \
    COMPUTE(CUR);                                                            \
} while (0)

    // Prologue: stage chunk 0.
    STAGE(ldsA, 0); SCHEDFENCE();

    // Phases 0..13: rolled 2-phase body (7 iters), ~3KB of code.
#pragma unroll 1
    for (int t = 0; t < 14; t += 2) {
        PHASE_STG(ldsA, ldsB, t);
        PHASE_STG(ldsB, ldsA, t + 1);
    }
    // Phase 14: compute chunk 14 from A, stage 15 into B.
    PHASE_STG(ldsA, ldsB, 14);
    // Phase 15: drain stage(15), compute from B.
    XLOAD(15); SCHEDFENCE();
    WAITV(16); BAR();
    COMPUTE(ldsB);

    // Epilogue: bias + coalesced store.
    const float4 b0v = *reinterpret_cast<const float4*>(bias + (size_t)l * kC + d0);
    const float4 b1v = *reinterpret_cast<const float4*>(bias + (size_t)l * kC + d0 + 4);
    const float bv[kND] = {b0v.x, b0v.y, b0v.z, b0v.w, b1v.x, b1v.y, b1v.z, b1v.w};

#pragma unroll
    for (int i = 0; i < kNB; ++i) {
        float* op = out + (size_t)(b0 + i) * (kC * kL) + l;
#pragma unroll
        for (int j = 0; j < kND; ++j)
            op[(size_t)(d0 + j) * kL] = acc[i][j] + bv[j];  // coalesced over l
    }

#undef STAGE
#undef XLOAD
#undef COMPUTE
#undef PHASE_STG
}

}  // namespace

extern "C" void kernel_launch(void* const* d_in, const int* in_sizes, int n_in,
                              void* d_out, int out_size, void* d_ws, size_t ws_size,
                              hipStream_t stream) {
    // inputs: 0=x (B,C,H,W) fp32, 1=px (unused), 2=weight (L*C, C) fp32,
    //         3=bias (L*C) fp32
    const float* x    = (const float*)d_in[0];
    const float* wgt  = (const float*)d_in[2];
    const float* bias = (const float*)d_in[3];
    float* out = (float*)d_out;

    dim3 grid(kL / 64, 128 / kNB);  // 64 x 16 = 1024 blocks = 4/CU
    dim3 block(256);
    hipLaunchKernelGGL(dyna_dec, grid, block, 0, stream, x, wgt, bias, out);
}